// Round 6
// baseline (475.798 us; speedup 1.0000x reference)
//
#include <hip/hip_runtime.h>
#include <hip/hip_bf16.h>
#include <math.h>

#define NTOK   4096
#define SEQ    1024
#define DMODEL 256
#define NHEAD  8
#define FDIM   1024
#define NLAYER 4

typedef __attribute__((ext_vector_type(8))) short short8v;
typedef __attribute__((ext_vector_type(4))) float f32x4;

#define LDS3(p) ((__attribute__((address_space(3))) unsigned int*)(p))
#define GAS1(p) ((const __attribute__((address_space(1))) unsigned int*)(p))

__device__ __forceinline__ void gl_lds16(const void* g, void* l) {
    __builtin_amdgcn_global_load_lds(GAS1(g), LDS3(l), 16, 0, 0);
}
__device__ __forceinline__ short f2bf(float v) {
    __hip_bfloat16 h = __float2bfloat16(v);
    return __builtin_bit_cast(short, h);
}

// ---------------------------------------------------------------- weight transpose fp32[K][M] -> bf16[M][K] (+ zero pad rows M..Mpad)
struct TD { const float* src; __hip_bfloat16* dst; int K; int M; int Mpad; };
struct TDs { TD d[29]; };

__global__ __launch_bounds__(256) void transpose_kernel(TDs p) {
    __shared__ float ld[32][33];
    TD d = p.d[blockIdx.y];
    int tm = (d.Mpad + 31) >> 5;
    int kt = blockIdx.x / tm, mt = blockIdx.x % tm;
    if (kt * 32 >= d.K) return;
    int tx = threadIdx.x & 31, ty = threadIdx.x >> 5;
    #pragma unroll
    for (int r = 0; r < 4; ++r) {
        int k = kt * 32 + ty + r * 8, m = mt * 32 + tx;
        if (m < d.M) ld[ty + r * 8][tx] = d.src[(long)k * d.M + m];
    }
    __syncthreads();
    #pragma unroll
    for (int r = 0; r < 4; ++r) {
        int m = mt * 32 + ty + r * 8, k = kt * 32 + tx;
        if (m < d.M) d.dst[(long)m * d.K + k] = __float2bfloat16(ld[tx][ty + r * 8]);
        else if (m < d.Mpad) d.dst[(long)m * d.K + k] = __float2bfloat16(0.f);
    }
}

// ---------------------------------------------------------------- MFMA GEMM (2-phase dbuf)
// EPI 0: fp32 store | 2: gelu->bf16 | 5: heads scatter (cols<66) | 6: QKV split
template <int TM, int TN, int EPI>
__global__ __launch_bounds__(256) void mm_kernel(
    const __hip_bfloat16* __restrict__ A, const __hip_bfloat16* __restrict__ Bw,
    const float* __restrict__ bias, float* __restrict__ Cf,
    __hip_bfloat16* __restrict__ Cb, int N, int K, int M,
    const float* __restrict__ b2, const float* __restrict__ b3,
    __hip_bfloat16* __restrict__ Ck, __hip_bfloat16* __restrict__ Cv)
{
    constexpr int BK = 64;
    __shared__ __align__(16) short As[2][TM * BK];
    __shared__ __align__(16) short Bs[2][TN * BK];
    const int tid = threadIdx.x;
    const int lane = tid & 63, wid = tid >> 6;
    const int wr = wid >> 1, wc = wid & 1;
    const int n0 = blockIdx.y * TM, m0 = blockIdx.x * TN;
    const int l15 = lane & 15, g = lane >> 4;
    constexpr int FM = (TM / 32 > 0) ? TM / 32 : 1;
    constexpr int FN = TN / 32;
    f32x4 acc[FM][FN] = {};
    const int nt = K >> 6;

    auto stage = [&](int buf, int k0) {
        constexpr int CA = TM * 8;
        #pragma unroll
        for (int j = 0; j < (CA + 255) / 256; ++j) {
            int cid = tid + j * 256;
            if (CA % 256 == 0 || cid < CA) {
                int r = cid >> 3, sl = cid & 7, ss = sl ^ (r & 7);
                gl_lds16(A + (long)(n0 + r) * K + k0 + ss * 8, (char*)As[buf] + cid * 16);
            }
        }
        constexpr int CB = TN * 8;
        #pragma unroll
        for (int j = 0; j < CB / 256; ++j) {
            int cid = tid + j * 256;
            int r = cid >> 3, sl = cid & 7, ss = sl ^ (r & 7);
            gl_lds16(Bw + (long)(m0 + r) * K + k0 + ss * 8, (char*)Bs[buf] + cid * 16);
        }
    };

    stage(0, 0);
    __syncthreads();
    for (int t = 0; t < nt; ++t) {
        int cur = t & 1;
        if (t + 1 < nt) stage(cur ^ 1, (t + 1) * BK);
        #pragma unroll
        for (int ks = 0; ks < 2; ++ks) {
            short8v af[FM], bfr[FN];
            #pragma unroll
            for (int mi = 0; mi < FM; ++mi) {
                int row = wr * (TM / 2) + mi * 16 + l15;
                int slot = (ks * 4 + g) ^ (row & 7);
                af[mi] = *(const short8v*)((const char*)As[cur] + row * (BK * 2) + slot * 16);
            }
            #pragma unroll
            for (int ni = 0; ni < FN; ++ni) {
                int row = wc * (TN / 2) + ni * 16 + l15;
                int slot = (ks * 4 + g) ^ (row & 7);
                bfr[ni] = *(const short8v*)((const char*)Bs[cur] + row * (BK * 2) + slot * 16);
            }
            #pragma unroll
            for (int mi = 0; mi < FM; ++mi)
                #pragma unroll
                for (int ni = 0; ni < FN; ++ni)
                    acc[mi][ni] = __builtin_amdgcn_mfma_f32_16x16x32_bf16(
                        af[mi], bfr[ni], acc[mi][ni], 0, 0, 0);
        }
        __syncthreads();
    }

    #pragma unroll
    for (int mi = 0; mi < FM; ++mi) {
        #pragma unroll
        for (int ni = 0; ni < FN; ++ni) {
            int colb = m0 + wc * (TN / 2) + ni * 16 + l15;
            float bv;
            if (EPI == 6) bv = (colb < 256) ? bias[colb] : (colb < 512) ? b2[colb - 256] : b3[colb - 512];
            else bv = bias[colb];
            if (EPI == 6 && colb >= 512) {
                int c2 = colb - 512;
                int h = c2 >> 5, dd = c2 & 31;
                int row0 = n0 + wr * (TM / 2) + mi * 16 + g * 4;
                int bb = row0 >> 10, ss = row0 & 1023;
                short4 pk;
                pk.x = f2bf(acc[mi][ni][0] + bv);
                pk.y = f2bf(acc[mi][ni][1] + bv);
                pk.z = f2bf(acc[mi][ni][2] + bv);
                pk.w = f2bf(acc[mi][ni][3] + bv);
                *(short4*)((short*)Cv + ((long)((bb * 8 + h) * 32 + dd) << 10) + ss) = pk;
            } else {
                #pragma unroll
                for (int i = 0; i < 4; ++i) {
                    int row = n0 + wr * (TM / 2) + mi * 16 + g * 4 + i;
                    float v = acc[mi][ni][i] + bv;
                    if (EPI == 0) Cf[(long)row * M + colb] = v;
                    else if (EPI == 2) {
                        v = 0.5f * v * (1.f + erff(v * 0.70710678f));
                        Cb[(long)row * M + colb] = __float2bfloat16(v);
                    } else if (EPI == 5) {
                        if (colb < 66) {
                            int hd = colb / 22, jj = colb - hd * 22;
                            Cf[(long)hd * (NTOK * 22) + (long)row * 22 + jj] = v;
                        }
                    } else if (EPI == 6) {
                        __hip_bfloat16* dst = (colb < 256) ? Cb : Ck;
                        int cc = (colb < 256) ? colb : colb - 256;
                        dst[(long)row * 256 + cc] = __float2bfloat16(v);
                    }
                }
            }
        }
    }
}

// ---------------------------------------------------------------- wide GEMM core macro-ish helpers
// shared 2-phase full-width (256-col) GEMM body; TM=16, 4 waves side by side.
#define WIDE_GEMM_BODY(Abuf, Bwp, Kval)                                           \
    constexpr int BK = 64;                                                        \
    const int tid = threadIdx.x;                                                  \
    const int lane = tid & 63, wid = tid >> 6;                                    \
    const int l15 = lane & 15, g = lane >> 4;                                     \
    const int n0 = blockIdx.x * 16;                                               \
    f32x4 acc[4] = {};                                                            \
    const int nt = (Kval) >> 6;                                                   \
    auto stage = [&](int buf, int k0) {                                           \
        if (tid < 128) {                                                          \
            int r = tid >> 3, sl = tid & 7, ss = sl ^ (r & 7);                    \
            gl_lds16((Abuf) + (long)(n0 + r) * (Kval) + k0 + ss * 8,              \
                     (char*)As[buf] + tid * 16);                                  \
        }                                                                         \
        _Pragma("unroll")                                                         \
        for (int j = 0; j < 8; ++j) {                                             \
            int cid = tid + j * 256;                                              \
            int r = cid >> 3, sl = cid & 7, ss = sl ^ (r & 7);                    \
            gl_lds16((Bwp) + (long)r * (Kval) + k0 + ss * 8,                      \
                     (char*)Bs[buf] + cid * 16);                                  \
        }                                                                         \
    };                                                                            \
    stage(0, 0);                                                                  \
    __syncthreads();                                                              \
    for (int t = 0; t < nt; ++t) {                                                \
        int cur = t & 1;                                                          \
        if (t + 1 < nt) stage(cur ^ 1, (t + 1) * BK);                             \
        _Pragma("unroll")                                                         \
        for (int ks = 0; ks < 2; ++ks) {                                          \
            short8v af;                                                           \
            {                                                                     \
                int slot = (ks * 4 + g) ^ (l15 & 7);                              \
                af = *(const short8v*)((const char*)As[cur] + l15 * (BK * 2) + slot * 16); \
            }                                                                     \
            _Pragma("unroll")                                                     \
            for (int ni = 0; ni < 4; ++ni) {                                      \
                int brow = wid * 64 + ni * 16 + l15;                              \
                int slot = (ks * 4 + g) ^ (brow & 7);                             \
                short8v bfr = *(const short8v*)((const char*)Bs[cur] + brow * (BK * 2) + slot * 16); \
                acc[ni] = __builtin_amdgcn_mfma_f32_16x16x32_bf16(af, bfr, acc[ni], 0, 0, 0); \
            }                                                                     \
        }                                                                         \
        __syncthreads();                                                          \
    }

__device__ __forceinline__ void wide_rowstats(
    float pvt[4][4], float2 red2[4][16], int wid, int l15, int g,
    float mean[4], float rstd[4])
{
    float rs[4] = {0.f, 0.f, 0.f, 0.f}, rq[4] = {0.f, 0.f, 0.f, 0.f};
    #pragma unroll
    for (int ni = 0; ni < 4; ++ni)
        #pragma unroll
        for (int i = 0; i < 4; ++i) { rs[i] += pvt[ni][i]; rq[i] += pvt[ni][i] * pvt[ni][i]; }
    #pragma unroll
    for (int i = 0; i < 4; ++i) {
        #pragma unroll
        for (int off = 8; off; off >>= 1) {
            rs[i] += __shfl_xor(rs[i], off);
            rq[i] += __shfl_xor(rq[i], off);
        }
    }
    __syncthreads();
    if (l15 == 0) {
        #pragma unroll
        for (int i = 0; i < 4; ++i)
            red2[wid][g * 4 + i] = make_float2(rs[i], rq[i]);
    }
    __syncthreads();
    #pragma unroll
    for (int i = 0; i < 4; ++i) {
        int lr = g * 4 + i;
        float s1 = red2[0][lr].x + red2[1][lr].x + red2[2][lr].x + red2[3][lr].x;
        float s2 = red2[0][lr].y + red2[1][lr].y + red2[2][lr].y + red2[3][lr].y;
        float mn = s1 * (1.f / 256.f);
        float var = s2 * (1.f / 256.f) - mn * mn;
        mean[i] = mn;
        rstd[i] = rsqrtf(var + 1e-5f);
    }
}

// ---------------------------------------------------------------- wide GEMM + residual + LN
__global__ __launch_bounds__(256) void mm_wide_ln_kernel(
    const __hip_bfloat16* __restrict__ A, const __hip_bfloat16* __restrict__ Bw,
    const float* __restrict__ bias, float* __restrict__ xio,
    __hip_bfloat16* __restrict__ nrm, const float* __restrict__ lng,
    const float* __restrict__ lnb, int K)
{
    __shared__ __align__(16) short As[2][16 * 64];
    __shared__ __align__(16) short Bs[2][256 * 64];
    __shared__ float2 red2[4][16];
    WIDE_GEMM_BODY(A, Bw, K)

    float pvt[4][4];
    #pragma unroll
    for (int ni = 0; ni < 4; ++ni) {
        int col = wid * 64 + ni * 16 + l15;
        float bv = bias[col];
        #pragma unroll
        for (int i = 0; i < 4; ++i) {
            int row = n0 + g * 4 + i;
            pvt[ni][i] = acc[ni][i] + bv + xio[(long)row * 256 + col];
        }
    }
    float mean[4], rstd[4];
    wide_rowstats(pvt, red2, wid, l15, g, mean, rstd);
    #pragma unroll
    for (int i = 0; i < 4; ++i) {
        int row = n0 + g * 4 + i;
        #pragma unroll
        for (int ni = 0; ni < 4; ++ni) {
            int col = wid * 64 + ni * 16 + l15;
            float v = pvt[ni][i];
            xio[(long)row * 256 + col] = v;
            nrm[(long)row * 256 + col] =
                __float2bfloat16((v - mean[i]) * rstd[i] * lng[col] + lnb[col]);
        }
    }
}

// ---------------------------------------------------------------- wide embed GEMM 1: LN + gematria -> catin
__global__ __launch_bounds__(256) void wide_gem_kernel(
    const __hip_bfloat16* __restrict__ A, const __hip_bfloat16* __restrict__ Bw,
    const float* __restrict__ bias, const float* __restrict__ lng,
    const float* __restrict__ lnb, const float* __restrict__ gem,
    __hip_bfloat16* __restrict__ catin)
{
    __shared__ __align__(16) short As[2][16 * 64];
    __shared__ __align__(16) short Bs[2][256 * 64];
    __shared__ float2 red2[4][16];
    WIDE_GEMM_BODY(A, Bw, 768)

    const float LC = 0.0359778921f;
    float pvt[4][4];
    #pragma unroll
    for (int ni = 0; ni < 4; ++ni) {
        int col = wid * 64 + ni * 16 + l15;
        float bv = bias[col];
        #pragma unroll
        for (int i = 0; i < 4; ++i) pvt[ni][i] = acc[ni][i] + bv;
    }
    float mean[4], rstd[4];
    wide_rowstats(pvt, red2, wid, l15, g, mean, rstd);
    float gv[4];
    #pragma unroll
    for (int i = 0; i < 4; ++i) gv[i] = gem[n0 + g * 4 + i];
    #pragma unroll
    for (int ni = 0; ni < 4; ++ni) {
        int col = wid * 64 + ni * 16 + l15;
        int j = col & 127;
        float c = 500.f * __expf(-(float)(2 * j) * LC);
        #pragma unroll
        for (int i = 0; i < 4; ++i) {
            int row = n0 + g * 4 + i;
            catin[(long)row * 512 + col] = __float2bfloat16(
                (pvt[ni][i] - mean[i]) * rstd[i] * lng[col] + lnb[col]);
            float ang = gv[i] * c;
            float gval = (col < 128) ? __sinf(ang) : __cosf(ang);
            catin[(long)row * 512 + 256 + col] = __float2bfloat16(gval);
        }
    }
}

// ---------------------------------------------------------------- wide embed GEMM 2: +PE, LN -> x, LN -> nrm
__global__ __launch_bounds__(256) void wide_pe_kernel(
    const __hip_bfloat16* __restrict__ A, const __hip_bfloat16* __restrict__ Bw,
    const float* __restrict__ bias, const float* __restrict__ lng,
    const float* __restrict__ lnb, const float* __restrict__ g1,
    const float* __restrict__ b1, float* __restrict__ x,
    __hip_bfloat16* __restrict__ nrm)
{
    __shared__ __align__(16) short As[2][16 * 64];
    __shared__ __align__(16) short Bs[2][256 * 64];
    __shared__ float2 red2[4][16];
    WIDE_GEMM_BODY(A, Bw, 512)

    const float LC = 0.0359778921f;
    float pvt[4][4];
    #pragma unroll
    for (int ni = 0; ni < 4; ++ni) {
        int col = wid * 64 + ni * 16 + l15;
        float bv = bias[col];
        float dv = __expf(-(float)(col & ~1) * LC);
        #pragma unroll
        for (int i = 0; i < 4; ++i) {
            int row = n0 + g * 4 + i;
            float pos = (float)(1023 - (row & 1023));
            float pe = (col & 1) ? __cosf(pos * dv) : __sinf(pos * dv);
            pvt[ni][i] = acc[ni][i] + bv + pe;
        }
    }
    float mean[4], rstd[4];
    wide_rowstats(pvt, red2, wid, l15, g, mean, rstd);
    #pragma unroll
    for (int ni = 0; ni < 4; ++ni) {
        int col = wid * 64 + ni * 16 + l15;
        #pragma unroll
        for (int i = 0; i < 4; ++i) {
            float xv = (pvt[ni][i] - mean[i]) * rstd[i] * lng[col] + lnb[col];
            pvt[ni][i] = xv;
            x[(long)(n0 + g * 4 + i) * 256 + col] = xv;
        }
    }
    __syncthreads();
    wide_rowstats(pvt, red2, wid, l15, g, mean, rstd);
    #pragma unroll
    for (int ni = 0; ni < 4; ++ni) {
        int col = wid * 64 + ni * 16 + l15;
        #pragma unroll
        for (int i = 0; i < 4; ++i) {
            int row = n0 + g * 4 + i;
            nrm[(long)row * 256 + col] = __float2bfloat16(
                (pvt[ni][i] - mean[i]) * rstd[i] * g1[col] + b1[col]);
        }
    }
}

// ---------------------------------------------------------------- MFMA flash attention
// 1 wave per block; 16 q-rows; K/V/Q direct global->reg; barrier-free;
// distance-bias tile skipping (skipped keys' softmax weight <= e^-25).
__global__ __launch_bounds__(64) void attn_mfma_kernel(
    const __hip_bfloat16* __restrict__ Q, const __hip_bfloat16* __restrict__ Kx,
    const __hip_bfloat16* __restrict__ Vt, __hip_bfloat16* __restrict__ Oa,
    const float* __restrict__ dsc, const float* __restrict__ dss)
{
    __shared__ __align__(16) short Ps[16 * 64];
    const int lane = threadIdx.x;
    const int qt = blockIdx.x;            // 16-row q tile
    const int bh = blockIdx.y, b = bh >> 3, h = bh & 7;
    const int l15 = lane & 15, g = lane >> 4;
    const float pen = fabsf(dsc[h] * (1.f - 0.5f * dss[h]));
    const float scale = 0.17677669529663689f;

    short8v bq = *(const short8v*)(Q + ((long)(b * SEQ + qt * 16 + l15) * DMODEL + h * 32 + g * 8));

    float m = -1e30f, l = 0.f;
    f32x4 oacc[2] = {};
    const float qpos = (float)(qt * 16 + l15);
    char* pbase = (char*)Ps + l15 * 128;

    int klo = 0, khi = 15;
    {
        float D = 30.f / pen;     // +inf when pen==0
        float kmin = (float)(qt * 16) - D;
        float kmax = (float)(qt * 16 + 15) + D;
        klo = max(0, (int)floorf(kmin * (1.f / 64.f)));
        khi = min(15, (int)floorf(kmax * (1.f / 64.f)));
    }

    for (int kt = klo; kt <= khi; ++kt) {
        short8v ak[4];
        #pragma unroll
        for (int ni = 0; ni < 4; ++ni) {
            int key = kt * 64 + ni * 16 + l15;
            ak[ni] = *(const short8v*)(Kx + ((long)(b * SEQ + key) * DMODEL + h * 32 + g * 8));
        }
        short8v vb[2][2];
        #pragma unroll
        for (int ks = 0; ks < 2; ++ks)
            #pragma unroll
            for (int n2 = 0; n2 < 2; ++n2) {
                int d = n2 * 16 + l15;
                vb[ks][n2] = *(const short8v*)(Vt + ((long)(bh * 32 + d) << 10) + kt * 64 + ks * 32 + g * 8);
            }

        float s[4][4];
        float smax = -1e30f;
        #pragma unroll
        for (int ni = 0; ni < 4; ++ni) {
            f32x4 z = {0.f, 0.f, 0.f, 0.f};
            f32x4 sa = __builtin_amdgcn_mfma_f32_16x16x32_bf16(ak[ni], bq, z, 0, 0, 0);
            float kbase = (float)(kt * 64 + ni * 16 + g * 4);
            #pragma unroll
            for (int i = 0; i < 4; ++i) {
                float v = sa[i] * scale - pen * fabsf(qpos - (kbase + (float)i));
                s[ni][i] = v;
                smax = fmaxf(smax, v);
            }
        }
        smax = fmaxf(smax, __shfl_xor(smax, 16));
        smax = fmaxf(smax, __shfl_xor(smax, 32));
        float mn = fmaxf(m, smax);
        float fac = __expf(m - mn);
        m = mn;
        float ps = 0.f;
        #pragma unroll
        for (int ni = 0; ni < 4; ++ni) {
            short4 pk;
            #pragma unroll
            for (int i = 0; i < 4; ++i) {
                float p = __expf(s[ni][i] - mn);
                ps += p;
                ((short*)&pk)[i] = f2bf(p);
            }
            int slot = (ni * 2 + (g >> 1)) ^ (l15 & 7);
            *(short4*)(pbase + slot * 16 + (g & 1) * 8) = pk;
        }
        ps += __shfl_xor(ps, 16);
        ps += __shfl_xor(ps, 32);
        l = l * fac + ps;

        float facr[4];
        #pragma unroll
        for (int i = 0; i < 4; ++i) facr[i] = __shfl(fac, g * 4 + i);
        #pragma unroll
        for (int n2 = 0; n2 < 2; ++n2)
            #pragma unroll
            for (int i = 0; i < 4; ++i) oacc[n2][i] *= facr[i];

        #pragma unroll
        for (int ks = 0; ks < 2; ++ks) {
            int slot = (ks * 4 + g) ^ (l15 & 7);
            short8v pa = *(const short8v*)(pbase + slot * 16);
            #pragma unroll
            for (int n2 = 0; n2 < 2; ++n2)
                oacc[n2] = __builtin_amdgcn_mfma_f32_16x16x32_bf16(pa, vb[ks][n2], oacc[n2], 0, 0, 0);
        }
    }
    float lr[4];
    #pragma unroll
    for (int i = 0; i < 4; ++i) lr[i] = __shfl(l, g * 4 + i);
    #pragma unroll
    for (int n2 = 0; n2 < 2; ++n2) {
        #pragma unroll
        for (int i = 0; i < 4; ++i) {
            float v = oacc[n2][i] / lr[i];
            long row = b * SEQ + qt * 16 + g * 4 + i;
            Oa[row * DMODEL + h * 32 + n2 * 16 + l15] = __float2bfloat16(v);
        }
    }
}

// ---------------------------------------------------------------- gather
__global__ __launch_bounds__(256) void gather_kernel(
    const int* __restrict__ roots, const float* __restrict__ letE,
    __hip_bfloat16* __restrict__ cat,
    const float* __restrict__ h1b, const float* __restrict__ h2b,
    const float* __restrict__ h3b, float* __restrict__ biascat)
{
    const int n = blockIdx.x, t = threadIdx.x;
    int r0 = roots[n * 3 + 0], r1 = roots[n * 3 + 1], r2 = roots[n * 3 + 2];
    cat[(long)n * 768 + t]       = __float2bfloat16(letE[r0 * DMODEL + t]);
    cat[(long)n * 768 + 256 + t] = __float2bfloat16(letE[r1 * DMODEL + t]);
    cat[(long)n * 768 + 512 + t] = __float2bfloat16(letE[r2 * DMODEL + t]);
    if (n == 0 && t < 66)
        biascat[t] = (t < 22) ? h1b[t] : (t < 44) ? h2b[t - 22] : h3b[t - 44];
}

// ---------------------------------------------------------------- launch
extern "C" void kernel_launch(void* const* d_in, const int* in_sizes, int n_in,
                              void* d_out, int out_size, void* d_ws, size_t ws_size,
                              hipStream_t stream)
{
    const int*   roots = (const int*)  d_in[0];
    const float* gem   = (const float*)d_in[1];
    const float* letE  = (const float*)d_in[2];
    const float* rpw   = (const float*)d_in[3];
    const float* rpb   = (const float*)d_in[4];
    const float* rlg   = (const float*)d_in[5];
    const float* rlb   = (const float*)d_in[6];
    const float* ipw   = (const float*)d_in[7];
    const float* ipb   = (const float*)d_in[8];
    const float* ilg   = (const float*)d_in[9];
    const float* ilb   = (const float*)d_in[10];
    const float* qw    = (const float*)d_in[11];
    const float* qb    = (const float*)d_in[12];
    const float* kw    = (const float*)d_in[13];
    const float* kb    = (const float*)d_in[14];
    const float* vw    = (const float*)d_in[15];
    const float* vb    = (const float*)d_in[16];
    const float* ow    = (const float*)d_in[17];
    const float* ob    = (const float*)d_in[18];
    const float* dsc   = (const float*)d_in[19];
    const float* dss   = (const float*)d_in[20];
    const float* ff1w  = (const float*)d_in[21];
    const float* ff1b  = (const float*)d_in[22];
    const float* ff2w  = (const float*)d_in[23];
    const float* ff2b  = (const float*)d_in[24];
    const float* ln1g  = (const float*)d_in[25];
    const float* ln1b  = (const float*)d_in[26];
    const float* ln2g  = (const float*)d_in[27];
    const float* ln2b  = (const float*)d_in[28];
    const float* olng  = (const float*)d_in[29];
    const float* olnb  = (const float*)d_in[30];
    const float* h1w   = (const float*)d_in[31];
    const float* h1b   = (const float*)d_in[32];
    const float* h2w   = (const float*)d_in[33];
    const float* h2b   = (const float*)d_in[34];
    const float* h3w   = (const float*)d_in[35];
    const float* h3b   = (const float*)d_in[36];

    char* wsb = (char*)d_ws;
    float*          x    = (float*)         (wsb + (0l  << 20));
    __hip_bfloat16* nrm  = (__hip_bfloat16*)(wsb + (8l  << 20));
    __hip_bfloat16* qbuf = (__hip_bfloat16*)(wsb + (10l << 20));
    __hip_bfloat16* kbuf = (__hip_bfloat16*)(wsb + (12l << 20));
    __hip_bfloat16* vtb  = (__hip_bfloat16*)(wsb + (14l << 20));
    __hip_bfloat16* aob  = (__hip_bfloat16*)(wsb + (16l << 20));
    __hip_bfloat16* hbb  = (__hip_bfloat16*)(wsb + (18l << 20));
    __hip_bfloat16* catb  = hbb;     // alias (embed phase only)
    __hip_bfloat16* catin = qbuf;    // alias (embed phase only, spans q+k)
    __hip_bfloat16* wb   = (__hip_bfloat16*)(wsb + (26l << 20));
    float*          biascat = (float*)      (wsb + (34l << 20));

    __hip_bfloat16* rpw_t  = wb;
    __hip_bfloat16* ipw_t  = wb + 196608;
    __hip_bfloat16* qkv_t  = wb + 327680;   // per layer: [768][256] (q|k|v)
    __hip_bfloat16* ow_t   = wb + 1114112;
    __hip_bfloat16* ff1w_t = wb + 1376256;
    __hip_bfloat16* ff2w_t = wb + 2424832;
    __hip_bfloat16* head_t = wb + 3473408;  // [128][256], rows 66..127 zeroed

    TDs td;
    td.d[0] = {rpw, rpw_t, 768, 256, 256};
    td.d[1] = {ipw, ipw_t, 512, 256, 256};
    for (int l = 0; l < 4; ++l) {
        td.d[2 + l]  = {qw + l * 65536,  qkv_t + l * 196608 + 0,      256, 256, 256};
        td.d[6 + l]  = {kw + l * 65536,  qkv_t + l * 196608 + 65536,  256, 256, 256};
        td.d[10 + l] = {vw + l * 65536,  qkv_t + l * 196608 + 131072, 256, 256, 256};
        td.d[14 + l] = {ow + l * 65536,  ow_t + l * 65536,  256, 256, 256};
        td.d[18 + l] = {ff1w + l * 262144, ff1w_t + l * 262144, 256, 1024, 1024};
        td.d[22 + l] = {ff2w + l * 262144, ff2w_t + l * 262144, 1024, 256, 256};
    }
    td.d[26] = {h1w, head_t + 0 * 22 * 256, 256, 22, 22};
    td.d[27] = {h2w, head_t + 1 * 22 * 256, 256, 22, 22};
    td.d[28] = {h3w, head_t + 2 * 22 * 256, 256, 22, 84};  // zero-pad global rows 66..127
    transpose_kernel<<<dim3(256, 29), 256, 0, stream>>>(td);

    gather_kernel<<<NTOK, 256, 0, stream>>>(roots, letE, catb, h1b, h2b, h3b, biascat);
    wide_gem_kernel<<<dim3(NTOK / 16), 256, 0, stream>>>(
        catb, rpw_t, rpb, rlg, rlb, gem, catin);
    wide_pe_kernel<<<dim3(NTOK / 16), 256, 0, stream>>>(
        catin, ipw_t, ipb, ilg, ilb, ln1g, ln1b, x, nrm);

    for (int l = 0; l < NLAYER; ++l) {
        mm_kernel<64, 64, 6><<<dim3(12, 64), 256, 0, stream>>>(
            nrm, qkv_t + l * 196608, qb + l * 256, nullptr, qbuf, NTOK, 256, 768,
            kb + l * 256, vb + l * 256, kbuf, vtb);
        attn_mfma_kernel<<<dim3(64, 32), 64, 0, stream>>>(qbuf, kbuf, vtb, aob,
                                                          dsc + l * 8, dss + l * 8);
        mm_wide_ln_kernel<<<dim3(NTOK / 16), 256, 0, stream>>>(
            aob, ow_t + l * 65536, ob + l * 256, x, nrm,
            ln2g + l * 256, ln2b + l * 256, 256);
        mm_kernel<64, 64, 2><<<dim3(16, 64), 256, 0, stream>>>(
            nrm, ff1w_t + l * 262144, ff1b + l * 1024, nullptr, hbb, NTOK, 256, 1024,
            nullptr, nullptr, nullptr, nullptr);
        const float* ng = (l == 3) ? olng : ln1g + (l + 1) * 256;
        const float* nb = (l == 3) ? olnb : ln1b + (l + 1) * 256;
        mm_wide_ln_kernel<<<dim3(NTOK / 16), 256, 0, stream>>>(
            hbb, ff2w_t + l * 262144, ff2b + l * 256, x, nrm, ng, nb, 1024);
    }
    mm_kernel<32, 64, 5><<<dim3(2, 128), 256, 0, stream>>>(
        nrm, head_t, biascat, (float*)d_out, nullptr, NTOK, 256, 128,
        nullptr, nullptr, nullptr, nullptr);
}

// Round 7
// 417.950 us; speedup vs baseline: 1.1384x; 1.1384x over previous
//
#include <hip/hip_runtime.h>
#include <hip/hip_bf16.h>
#include <math.h>

#define NTOK   4096
#define SEQ    1024
#define DMODEL 256
#define NHEAD  8
#define FDIM   1024
#define NLAYER 4
#define VOCAB  25

typedef __attribute__((ext_vector_type(8))) short short8v;
typedef __attribute__((ext_vector_type(4))) float f32x4;

#define LDS3(p) ((__attribute__((address_space(3))) unsigned int*)(p))
#define GAS1(p) ((const __attribute__((address_space(1))) unsigned int*)(p))

__device__ __forceinline__ void gl_lds16(const void* g, void* l) {
    __builtin_amdgcn_global_load_lds(GAS1(g), LDS3(l), 16, 0, 0);
}
__device__ __forceinline__ short f2bf(float v) {
    __hip_bfloat16 h = __float2bfloat16(v);
    return __builtin_bit_cast(short, h);
}

// ---------------------------------------------------------------- letE fp32 -> bf16
__global__ __launch_bounds__(256) void cvt_kernel(
    const float* __restrict__ src, __hip_bfloat16* __restrict__ dst, int n)
{
    int i = blockIdx.x * 256 + threadIdx.x;
    if (i < n) dst[i] = __float2bfloat16(src[i]);
}

// ---------------------------------------------------------------- weight transpose fp32[K][M] -> bf16[M][K] (+ zero pad rows M..Mpad)
struct TD { const float* src; __hip_bfloat16* dst; int K; int M; int Mpad; };
struct TDs { TD d[29]; };

__global__ __launch_bounds__(256) void transpose_kernel(TDs p) {
    __shared__ float ld[32][33];
    TD d = p.d[blockIdx.y];
    int tm = (d.Mpad + 31) >> 5;
    int kt = blockIdx.x / tm, mt = blockIdx.x % tm;
    if (kt * 32 >= d.K) return;
    int tx = threadIdx.x & 31, ty = threadIdx.x >> 5;
    #pragma unroll
    for (int r = 0; r < 4; ++r) {
        int k = kt * 32 + ty + r * 8, m = mt * 32 + tx;
        if (m < d.M) ld[ty + r * 8][tx] = d.src[(long)k * d.M + m];
    }
    __syncthreads();
    #pragma unroll
    for (int r = 0; r < 4; ++r) {
        int m = mt * 32 + ty + r * 8, k = kt * 32 + tx;
        if (m < d.M) d.dst[(long)m * d.K + k] = __float2bfloat16(ld[tx][ty + r * 8]);
        else if (m < d.Mpad) d.dst[(long)m * d.K + k] = __float2bfloat16(0.f);
    }
}

// ---------------------------------------------------------------- MFMA GEMM (2-phase dbuf)
// EPI 0: fp32 store | 2: gelu->bf16 | 5: heads scatter (cols<66) | 6: QKV split
template <int TM, int TN, int EPI>
__global__ __launch_bounds__(256) void mm_kernel(
    const __hip_bfloat16* __restrict__ A, const __hip_bfloat16* __restrict__ Bw,
    const float* __restrict__ bias, float* __restrict__ Cf,
    __hip_bfloat16* __restrict__ Cb, int N, int K, int M,
    const float* __restrict__ b2, const float* __restrict__ b3,
    __hip_bfloat16* __restrict__ Ck, __hip_bfloat16* __restrict__ Cv)
{
    constexpr int BK = 64;
    __shared__ __align__(16) short As[2][TM * BK];
    __shared__ __align__(16) short Bs[2][TN * BK];
    const int tid = threadIdx.x;
    const int lane = tid & 63, wid = tid >> 6;
    const int wr = wid >> 1, wc = wid & 1;
    const int n0 = blockIdx.y * TM, m0 = blockIdx.x * TN;
    const int l15 = lane & 15, g = lane >> 4;
    constexpr int FM = (TM / 32 > 0) ? TM / 32 : 1;
    constexpr int FN = TN / 32;
    f32x4 acc[FM][FN] = {};
    const int nt = K >> 6;

    auto stage = [&](int buf, int k0) {
        constexpr int CA = TM * 8;
        #pragma unroll
        for (int j = 0; j < (CA + 255) / 256; ++j) {
            int cid = tid + j * 256;
            if (CA % 256 == 0 || cid < CA) {
                int r = cid >> 3, sl = cid & 7, ss = sl ^ (r & 7);
                gl_lds16(A + (long)(n0 + r) * K + k0 + ss * 8, (char*)As[buf] + cid * 16);
            }
        }
        constexpr int CB = TN * 8;
        #pragma unroll
        for (int j = 0; j < CB / 256; ++j) {
            int cid = tid + j * 256;
            int r = cid >> 3, sl = cid & 7, ss = sl ^ (r & 7);
            gl_lds16(Bw + (long)(m0 + r) * K + k0 + ss * 8, (char*)Bs[buf] + cid * 16);
        }
    };

    stage(0, 0);
    __syncthreads();
    for (int t = 0; t < nt; ++t) {
        int cur = t & 1;
        if (t + 1 < nt) stage(cur ^ 1, (t + 1) * BK);
        #pragma unroll
        for (int ks = 0; ks < 2; ++ks) {
            short8v af[FM], bfr[FN];
            #pragma unroll
            for (int mi = 0; mi < FM; ++mi) {
                int row = wr * (TM / 2) + mi * 16 + l15;
                int slot = (ks * 4 + g) ^ (row & 7);
                af[mi] = *(const short8v*)((const char*)As[cur] + row * (BK * 2) + slot * 16);
            }
            #pragma unroll
            for (int ni = 0; ni < FN; ++ni) {
                int row = wc * (TN / 2) + ni * 16 + l15;
                int slot = (ks * 4 + g) ^ (row & 7);
                bfr[ni] = *(const short8v*)((const char*)Bs[cur] + row * (BK * 2) + slot * 16);
            }
            #pragma unroll
            for (int mi = 0; mi < FM; ++mi)
                #pragma unroll
                for (int ni = 0; ni < FN; ++ni)
                    acc[mi][ni] = __builtin_amdgcn_mfma_f32_16x16x32_bf16(
                        af[mi], bfr[ni], acc[mi][ni], 0, 0, 0);
        }
        __syncthreads();
    }

    #pragma unroll
    for (int mi = 0; mi < FM; ++mi) {
        #pragma unroll
        for (int ni = 0; ni < FN; ++ni) {
            int colb = m0 + wc * (TN / 2) + ni * 16 + l15;
            float bv;
            if (EPI == 6) bv = (colb < 256) ? bias[colb] : (colb < 512) ? b2[colb - 256] : b3[colb - 512];
            else if (EPI == 5) bv = (colb < 22) ? bias[colb] : (colb < 44) ? b2[colb - 22] : (colb < 66) ? b3[colb - 44] : 0.f;
            else bv = bias[colb];
            if (EPI == 6 && colb >= 512) {
                int c2 = colb - 512;
                int h = c2 >> 5, dd = c2 & 31;
                int row0 = n0 + wr * (TM / 2) + mi * 16 + g * 4;
                int bb = row0 >> 10, ss = row0 & 1023;
                short4 pk;
                pk.x = f2bf(acc[mi][ni][0] + bv);
                pk.y = f2bf(acc[mi][ni][1] + bv);
                pk.z = f2bf(acc[mi][ni][2] + bv);
                pk.w = f2bf(acc[mi][ni][3] + bv);
                *(short4*)((short*)Cv + ((long)((bb * 8 + h) * 32 + dd) << 10) + ss) = pk;
            } else {
                #pragma unroll
                for (int i = 0; i < 4; ++i) {
                    int row = n0 + wr * (TM / 2) + mi * 16 + g * 4 + i;
                    float v = acc[mi][ni][i] + bv;
                    if (EPI == 0) Cf[(long)row * M + colb] = v;
                    else if (EPI == 2) {
                        v = 0.5f * v * (1.f + erff(v * 0.70710678f));
                        Cb[(long)row * M + colb] = __float2bfloat16(v);
                    } else if (EPI == 5) {
                        if (colb < 66) {
                            int hd = colb / 22, jj = colb - hd * 22;
                            Cf[(long)hd * (NTOK * 22) + (long)row * 22 + jj] = v;
                        }
                    } else if (EPI == 6) {
                        __hip_bfloat16* dst = (colb < 256) ? Cb : Ck;
                        int cc = (colb < 256) ? colb : colb - 256;
                        dst[(long)row * 256 + cc] = __float2bfloat16(v);
                    }
                }
            }
        }
    }
}

// ---------------------------------------------------------------- wide GEMM core
#define WIDE_GEMM_BODY(Abuf, Bwp, Kval)                                           \
    constexpr int BK = 64;                                                        \
    const int tid = threadIdx.x;                                                  \
    const int lane = tid & 63, wid = tid >> 6;                                    \
    const int l15 = lane & 15, g = lane >> 4;                                     \
    const int n0 = blockIdx.x * 16;                                               \
    f32x4 acc[4] = {};                                                            \
    const int nt = (Kval) >> 6;                                                   \
    auto stage = [&](int buf, int k0) {                                           \
        if (tid < 128) {                                                          \
            int r = tid >> 3, sl = tid & 7, ss = sl ^ (r & 7);                    \
            gl_lds16((Abuf) + (long)(n0 + r) * (Kval) + k0 + ss * 8,              \
                     (char*)As[buf] + tid * 16);                                  \
        }                                                                         \
        _Pragma("unroll")                                                         \
        for (int j = 0; j < 8; ++j) {                                             \
            int cid = tid + j * 256;                                              \
            int r = cid >> 3, sl = cid & 7, ss = sl ^ (r & 7);                    \
            gl_lds16((Bwp) + (long)r * (Kval) + k0 + ss * 8,                      \
                     (char*)Bs[buf] + cid * 16);                                  \
        }                                                                         \
    };                                                                            \
    stage(0, 0);                                                                  \
    __syncthreads();                                                              \
    for (int t = 0; t < nt; ++t) {                                                \
        int cur = t & 1;                                                          \
        if (t + 1 < nt) stage(cur ^ 1, (t + 1) * BK);                             \
        _Pragma("unroll")                                                         \
        for (int ks = 0; ks < 2; ++ks) {                                          \
            short8v af;                                                           \
            {                                                                     \
                int slot = (ks * 4 + g) ^ (l15 & 7);                              \
                af = *(const short8v*)((const char*)As[cur] + l15 * (BK * 2) + slot * 16); \
            }                                                                     \
            _Pragma("unroll")                                                     \
            for (int ni = 0; ni < 4; ++ni) {                                      \
                int brow = wid * 64 + ni * 16 + l15;                              \
                int slot = (ks * 4 + g) ^ (brow & 7);                             \
                short8v bfr = *(const short8v*)((const char*)Bs[cur] + brow * (BK * 2) + slot * 16); \
                acc[ni] = __builtin_amdgcn_mfma_f32_16x16x32_bf16(af, bfr, acc[ni], 0, 0, 0); \
            }                                                                     \
        }                                                                         \
        __syncthreads();                                                          \
    }

__device__ __forceinline__ void wide_rowstats(
    float pvt[4][4], float2 red2[4][16], int wid, int l15, int g,
    float mean[4], float rstd[4])
{
    float rs[4] = {0.f, 0.f, 0.f, 0.f}, rq[4] = {0.f, 0.f, 0.f, 0.f};
    #pragma unroll
    for (int ni = 0; ni < 4; ++ni)
        #pragma unroll
        for (int i = 0; i < 4; ++i) { rs[i] += pvt[ni][i]; rq[i] += pvt[ni][i] * pvt[ni][i]; }
    #pragma unroll
    for (int i = 0; i < 4; ++i) {
        #pragma unroll
        for (int off = 8; off; off >>= 1) {
            rs[i] += __shfl_xor(rs[i], off);
            rq[i] += __shfl_xor(rq[i], off);
        }
    }
    __syncthreads();
    if (l15 == 0) {
        #pragma unroll
        for (int i = 0; i < 4; ++i)
            red2[wid][g * 4 + i] = make_float2(rs[i], rq[i]);
    }
    __syncthreads();
    #pragma unroll
    for (int i = 0; i < 4; ++i) {
        int lr = g * 4 + i;
        float s1 = red2[0][lr].x + red2[1][lr].x + red2[2][lr].x + red2[3][lr].x;
        float s2 = red2[0][lr].y + red2[1][lr].y + red2[2][lr].y + red2[3][lr].y;
        float mn = s1 * (1.f / 256.f);
        float var = s2 * (1.f / 256.f) - mn * mn;
        mean[i] = mn;
        rstd[i] = rsqrtf(var + 1e-5f);
    }
}

// ---------------------------------------------------------------- wide GEMM + residual + LN
__global__ __launch_bounds__(256) void mm_wide_ln_kernel(
    const __hip_bfloat16* __restrict__ A, const __hip_bfloat16* __restrict__ Bw,
    const float* __restrict__ bias, float* __restrict__ xio,
    __hip_bfloat16* __restrict__ nrm, const float* __restrict__ lng,
    const float* __restrict__ lnb, int K)
{
    __shared__ __align__(16) short As[2][16 * 64];
    __shared__ __align__(16) short Bs[2][256 * 64];
    __shared__ float2 red2[4][16];
    WIDE_GEMM_BODY(A, Bw, K)

    float pvt[4][4];
    #pragma unroll
    for (int ni = 0; ni < 4; ++ni) {
        int col = wid * 64 + ni * 16 + l15;
        float bv = bias[col];
        #pragma unroll
        for (int i = 0; i < 4; ++i) {
            int row = n0 + g * 4 + i;
            pvt[ni][i] = acc[ni][i] + bv + xio[(long)row * 256 + col];
        }
    }
    float mean[4], rstd[4];
    wide_rowstats(pvt, red2, wid, l15, g, mean, rstd);
    #pragma unroll
    for (int i = 0; i < 4; ++i) {
        int row = n0 + g * 4 + i;
        #pragma unroll
        for (int ni = 0; ni < 4; ++ni) {
            int col = wid * 64 + ni * 16 + l15;
            float v = pvt[ni][i];
            xio[(long)row * 256 + col] = v;
            nrm[(long)row * 256 + col] =
                __float2bfloat16((v - mean[i]) * rstd[i] * lng[col] + lnb[col]);
        }
    }
}

// ---------------------------------------------------------------- wide embed GEMM 1 (direct letE gather): LN + gematria -> catin
__global__ __launch_bounds__(256) void wide_gem_kernel(
    const int* __restrict__ roots, const __hip_bfloat16* __restrict__ letEbf,
    const __hip_bfloat16* __restrict__ Bw,
    const float* __restrict__ bias, const float* __restrict__ lng,
    const float* __restrict__ lnb, const float* __restrict__ gem,
    __hip_bfloat16* __restrict__ catin)
{
    __shared__ __align__(16) short As[2][16 * 64];
    __shared__ __align__(16) short Bs[2][256 * 64];
    __shared__ float2 red2[4][16];
    constexpr int BK = 64;
    const int tid = threadIdx.x;
    const int lane = tid & 63, wid = tid >> 6;
    const int l15 = lane & 15, g = lane >> 4;
    const int n0 = blockIdx.x * 16;
    f32x4 acc[4] = {};
    const int nt = 12;
    auto stage = [&](int buf, int k0) {
        if (tid < 128) {
            int r = tid >> 3, sl = tid & 7, ss = sl ^ (r & 7);
            int j = k0 >> 8, off = (k0 & 255) + ss * 8;
            int root = roots[(n0 + r) * 3 + j];
            gl_lds16(letEbf + (long)root * 256 + off, (char*)As[buf] + tid * 16);
        }
        #pragma unroll
        for (int j = 0; j < 8; ++j) {
            int cid = tid + j * 256;
            int r = cid >> 3, sl = cid & 7, ss = sl ^ (r & 7);
            gl_lds16(Bw + (long)r * 768 + k0 + ss * 8, (char*)Bs[buf] + cid * 16);
        }
    };
    stage(0, 0);
    __syncthreads();
    for (int t = 0; t < nt; ++t) {
        int cur = t & 1;
        if (t + 1 < nt) stage(cur ^ 1, (t + 1) * BK);
        #pragma unroll
        for (int ks = 0; ks < 2; ++ks) {
            short8v af;
            {
                int slot = (ks * 4 + g) ^ (l15 & 7);
                af = *(const short8v*)((const char*)As[cur] + l15 * (BK * 2) + slot * 16);
            }
            #pragma unroll
            for (int ni = 0; ni < 4; ++ni) {
                int brow = wid * 64 + ni * 16 + l15;
                int slot = (ks * 4 + g) ^ (brow & 7);
                short8v bfr = *(const short8v*)((const char*)Bs[cur] + brow * (BK * 2) + slot * 16);
                acc[ni] = __builtin_amdgcn_mfma_f32_16x16x32_bf16(af, bfr, acc[ni], 0, 0, 0);
            }
        }
        __syncthreads();
    }

    const float LC = 0.0359778921f;
    float pvt[4][4];
    #pragma unroll
    for (int ni = 0; ni < 4; ++ni) {
        int col = wid * 64 + ni * 16 + l15;
        float bv = bias[col];
        #pragma unroll
        for (int i = 0; i < 4; ++i) pvt[ni][i] = acc[ni][i] + bv;
    }
    float mean[4], rstd[4];
    wide_rowstats(pvt, red2, wid, l15, g, mean, rstd);
    float gv[4];
    #pragma unroll
    for (int i = 0; i < 4; ++i) gv[i] = gem[n0 + g * 4 + i];
    #pragma unroll
    for (int ni = 0; ni < 4; ++ni) {
        int col = wid * 64 + ni * 16 + l15;
        int j = col & 127;
        float c = 500.f * __expf(-(float)(2 * j) * LC);
        #pragma unroll
        for (int i = 0; i < 4; ++i) {
            int row = n0 + g * 4 + i;
            catin[(long)row * 512 + col] = __float2bfloat16(
                (pvt[ni][i] - mean[i]) * rstd[i] * lng[col] + lnb[col]);
            float ang = gv[i] * c;
            float gval = (col < 128) ? __sinf(ang) : __cosf(ang);
            catin[(long)row * 512 + 256 + col] = __float2bfloat16(gval);
        }
    }
}

// ---------------------------------------------------------------- wide embed GEMM 2: +PE, LN -> x, LN -> nrm
__global__ __launch_bounds__(256) void wide_pe_kernel(
    const __hip_bfloat16* __restrict__ A, const __hip_bfloat16* __restrict__ Bw,
    const float* __restrict__ bias, const float* __restrict__ lng,
    const float* __restrict__ lnb, const float* __restrict__ g1,
    const float* __restrict__ b1, float* __restrict__ x,
    __hip_bfloat16* __restrict__ nrm)
{
    __shared__ __align__(16) short As[2][16 * 64];
    __shared__ __align__(16) short Bs[2][256 * 64];
    __shared__ float2 red2[4][16];
    WIDE_GEMM_BODY(A, Bw, 512)

    const float LC = 0.0359778921f;
    float pvt[4][4];
    #pragma unroll
    for (int ni = 0; ni < 4; ++ni) {
        int col = wid * 64 + ni * 16 + l15;
        float bv = bias[col];
        float dv = __expf(-(float)(col & ~1) * LC);
        #pragma unroll
        for (int i = 0; i < 4; ++i) {
            int row = n0 + g * 4 + i;
            float pos = (float)(1023 - (row & 1023));
            float pe = (col & 1) ? __cosf(pos * dv) : __sinf(pos * dv);
            pvt[ni][i] = acc[ni][i] + bv + pe;
        }
    }
    float mean[4], rstd[4];
    wide_rowstats(pvt, red2, wid, l15, g, mean, rstd);
    #pragma unroll
    for (int ni = 0; ni < 4; ++ni) {
        int col = wid * 64 + ni * 16 + l15;
        #pragma unroll
        for (int i = 0; i < 4; ++i) {
            float xv = (pvt[ni][i] - mean[i]) * rstd[i] * lng[col] + lnb[col];
            pvt[ni][i] = xv;
            x[(long)(n0 + g * 4 + i) * 256 + col] = xv;
        }
    }
    __syncthreads();
    wide_rowstats(pvt, red2, wid, l15, g, mean, rstd);
    #pragma unroll
    for (int ni = 0; ni < 4; ++ni) {
        int col = wid * 64 + ni * 16 + l15;
        #pragma unroll
        for (int i = 0; i < 4; ++i) {
            int row = n0 + g * 4 + i;
            nrm[(long)row * 256 + col] = __float2bfloat16(
                (pvt[ni][i] - mean[i]) * rstd[i] * g1[col] + b1[col]);
        }
    }
}

// ---------------------------------------------------------------- MFMA flash attention (4-wave, LDS-staged K/V, swapped QK^T, tile skip)
__global__ __launch_bounds__(256) void attn_mfma_kernel(
    const __hip_bfloat16* __restrict__ Q, const __hip_bfloat16* __restrict__ Kx,
    const __hip_bfloat16* __restrict__ Vt, __hip_bfloat16* __restrict__ Oa,
    const float* __restrict__ dsc, const float* __restrict__ dss)
{
    __shared__ __align__(16) short Qs[64 * 32];
    __shared__ __align__(16) short Ks[2][64 * 32];
    __shared__ __align__(16) short Vs[2][32 * 64];
    __shared__ __align__(16) short Ps[4 * 16 * 64];
    const int tid = threadIdx.x, lane = tid & 63, wid = tid >> 6;
    const int qt = blockIdx.x, bh = blockIdx.y, b = bh >> 3, h = bh & 7;
    const float pen = fabsf(dsc[h] * (1.f - 0.5f * dss[h]));
    const int l15 = lane & 15, g = lane >> 4;
    const float scale = 0.17677669529663689f;

    auto stageKV = [&](int buf, int kt) {
        int r = tid >> 2, sl = tid & 3, ss = sl ^ (r & 3);
        gl_lds16(Kx + ((long)(b * SEQ + kt * 64 + r) * DMODEL + h * 32) + ss * 8,
                 (char*)Ks[buf] + tid * 16);
        int d = tid >> 3, sl8 = tid & 7, ss8 = sl8 ^ (d & 7);
        gl_lds16(Vt + ((long)(bh * 32 + d) << 10) + kt * 64 + ss8 * 8,
                 (char*)Vs[buf] + tid * 16);
    };

    int klo = 0, khi = 15;
    {
        float D = 30.f / pen;     // +inf when pen==0
        float kmin = (float)(qt * 64) - D;
        float kmax = (float)(qt * 64 + 63) + D;
        klo = max(0, (int)floorf(kmin * (1.f / 64.f)));
        khi = min(15, (int)floorf(kmax * (1.f / 64.f)));
    }

    {   // stage Q tile (64 rows x 32 d)
        int r = tid >> 2, sl = tid & 3, ss = sl ^ (r & 3);
        gl_lds16(Q + ((long)(b * SEQ + qt * 64 + r) * DMODEL + h * 32) + ss * 8,
                 (char*)Qs + tid * 16);
    }
    stageKV(0, klo);
    __syncthreads();

    short8v bq;
    {
        int row = wid * 16 + l15;
        int slot = g ^ (row & 3);
        bq = *(const short8v*)((const char*)Qs + row * 64 + slot * 16);
    }

    float m = -1e30f, l = 0.f;            // per-thread: q-column = l15
    f32x4 oacc[2] = {};
    const float qpos = (float)(qt * 64 + wid * 16 + l15);
    char* pbase = (char*)Ps + wid * 2048 + l15 * 128;

    for (int kt = klo; kt <= khi; ++kt) {
        int cur = (kt - klo) & 1;
        if (kt < khi) stageKV(cur ^ 1, kt + 1);

        float s[4][4];
        float smax = -1e30f;
        #pragma unroll
        for (int ni = 0; ni < 4; ++ni) {
            int krow = ni * 16 + l15;
            int slot = g ^ (krow & 3);
            short8v ak = *(const short8v*)((const char*)Ks[cur] + krow * 64 + slot * 16);
            f32x4 z = {0.f, 0.f, 0.f, 0.f};
            f32x4 sa = __builtin_amdgcn_mfma_f32_16x16x32_bf16(ak, bq, z, 0, 0, 0);
            float kbase = (float)(kt * 64 + ni * 16 + g * 4);
            #pragma unroll
            for (int i = 0; i < 4; ++i) {
                float v = sa[i] * scale - pen * fabsf(qpos - (kbase + (float)i));
                s[ni][i] = v;
                smax = fmaxf(smax, v);
            }
        }
        smax = fmaxf(smax, __shfl_xor(smax, 16));
        smax = fmaxf(smax, __shfl_xor(smax, 32));
        float mn = fmaxf(m, smax);
        float fac = __expf(m - mn);
        m = mn;
        float ps = 0.f;
        #pragma unroll
        for (int ni = 0; ni < 4; ++ni) {
            short4 pk;
            #pragma unroll
            for (int i = 0; i < 4; ++i) {
                float p = __expf(s[ni][i] - mn);
                ps += p;
                ((short*)&pk)[i] = f2bf(p);
            }
            int slot = (ni * 2 + (g >> 1)) ^ (l15 & 7);
            *(short4*)(pbase + slot * 16 + (g & 1) * 8) = pk;
        }
        ps += __shfl_xor(ps, 16);
        ps += __shfl_xor(ps, 32);
        l = l * fac + ps;

        float facr[4];
        #pragma unroll
        for (int i = 0; i < 4; ++i) facr[i] = __shfl(fac, g * 4 + i);
        #pragma unroll
        for (int n2 = 0; n2 < 2; ++n2)
            #pragma unroll
            for (int i = 0; i < 4; ++i) oacc[n2][i] *= facr[i];

        #pragma unroll
        for (int ks = 0; ks < 2; ++ks) {
            int slot = (ks * 4 + g) ^ (l15 & 7);
            short8v pa = *(const short8v*)(pbase + slot * 16);
            #pragma unroll
            for (int n2 = 0; n2 < 2; ++n2) {
                int d = n2 * 16 + l15;
                int vslot = (ks * 4 + g) ^ (d & 7);
                short8v vb = *(const short8v*)((const char*)Vs[cur] + d * 128 + vslot * 16);
                oacc[n2] = __builtin_amdgcn_mfma_f32_16x16x32_bf16(pa, vb, oacc[n2], 0, 0, 0);
            }
        }
        __syncthreads();
    }
    float lr[4];
    #pragma unroll
    for (int i = 0; i < 4; ++i) lr[i] = __shfl(l, g * 4 + i);
    #pragma unroll
    for (int n2 = 0; n2 < 2; ++n2) {
        #pragma unroll
        for (int i = 0; i < 4; ++i) {
            float v = oacc[n2][i] / lr[i];
            long row = b * SEQ + qt * 64 + wid * 16 + g * 4 + i;
            Oa[row * DMODEL + h * 32 + n2 * 16 + l15] = __float2bfloat16(v);
        }
    }
}

// ---------------------------------------------------------------- launch
extern "C" void kernel_launch(void* const* d_in, const int* in_sizes, int n_in,
                              void* d_out, int out_size, void* d_ws, size_t ws_size,
                              hipStream_t stream)
{
    const int*   roots = (const int*)  d_in[0];
    const float* gem   = (const float*)d_in[1];
    const float* letE  = (const float*)d_in[2];
    const float* rpw   = (const float*)d_in[3];
    const float* rpb   = (const float*)d_in[4];
    const float* rlg   = (const float*)d_in[5];
    const float* rlb   = (const float*)d_in[6];
    const float* ipw   = (const float*)d_in[7];
    const float* ipb   = (const float*)d_in[8];
    const float* ilg   = (const float*)d_in[9];
    const float* ilb   = (const float*)d_in[10];
    const float* qw    = (const float*)d_in[11];
    const float* qb    = (const float*)d_in[12];
    const float* kw    = (const float*)d_in[13];
    const float* kb    = (const float*)d_in[14];
    const float* vw    = (const float*)d_in[15];
    const float* vb    = (const float*)d_in[16];
    const float* ow    = (const float*)d_in[17];
    const float* ob    = (const float*)d_in[18];
    const float* dsc   = (const float*)d_in[19];
    const float* dss   = (const float*)d_in[20];
    const float* ff1w  = (const float*)d_in[21];
    const float* ff1b  = (const float*)d_in[22];
    const float* ff2w  = (const float*)d_in[23];
    const float* ff2b  = (const float*)d_in[24];
    const float* ln1g  = (const float*)d_in[25];
    const float* ln1b  = (const float*)d_in[26];
    const float* ln2g  = (const float*)d_in[27];
    const float* ln2b  = (const float*)d_in[28];
    const float* olng  = (const float*)d_in[29];
    const float* olnb  = (const float*)d_in[30];
    const float* h1w   = (const float*)d_in[31];
    const float* h1b   = (const float*)d_in[32];
    const float* h2w   = (const float*)d_in[33];
    const float* h2b   = (const float*)d_in[34];
    const float* h3w   = (const float*)d_in[35];
    const float* h3b   = (const float*)d_in[36];

    char* wsb = (char*)d_ws;
    float*          x    = (float*)         (wsb + (0l  << 20));
    __hip_bfloat16* nrm  = (__hip_bfloat16*)(wsb + (8l  << 20));
    __hip_bfloat16* qbuf = (__hip_bfloat16*)(wsb + (10l << 20));
    __hip_bfloat16* kbuf = (__hip_bfloat16*)(wsb + (12l << 20));
    __hip_bfloat16* vtb  = (__hip_bfloat16*)(wsb + (14l << 20));
    __hip_bfloat16* aob  = (__hip_bfloat16*)(wsb + (16l << 20));
    __hip_bfloat16* hbb  = (__hip_bfloat16*)(wsb + (18l << 20));
    __hip_bfloat16* catin = qbuf;    // alias (embed phase only, spans q+k)
    __hip_bfloat16* wb   = (__hip_bfloat16*)(wsb + (26l << 20));

    __hip_bfloat16* rpw_t  = wb;
    __hip_bfloat16* ipw_t  = wb + 196608;
    __hip_bfloat16* qkv_t  = wb + 327680;   // per layer: [768][256] (q|k|v)
    __hip_bfloat16* ow_t   = wb + 1114112;
    __hip_bfloat16* ff1w_t = wb + 1376256;
    __hip_bfloat16* ff2w_t = wb + 2424832;
    __hip_bfloat16* head_t = wb + 3473408;  // [128][256], rows 66..127 zeroed
    __hip_bfloat16* letEbf = wb + 3506176;  // [25][256]

    TDs td;
    td.d[0] = {rpw, rpw_t, 768, 256, 256};
    td.d[1] = {ipw, ipw_t, 512, 256, 256};
    for (int l = 0; l < 4; ++l) {
        td.d[2 + l]  = {qw + l * 65536,  qkv_t + l * 196608 + 0,      256, 256, 256};
        td.d[6 + l]  = {kw + l * 65536,  qkv_t + l * 196608 + 65536,  256, 256, 256};
        td.d[10 + l] = {vw + l * 65536,  qkv_t + l * 196608 + 131072, 256, 256, 256};
        td.d[14 + l] = {ow + l * 65536,  ow_t + l * 65536,  256, 256, 256};
        td.d[18 + l] = {ff1w + l * 262144, ff1w_t + l * 262144, 256, 1024, 1024};
        td.d[22 + l] = {ff2w + l * 262144, ff2w_t + l * 262144, 1024, 256, 256};
    }
    td.d[26] = {h1w, head_t + 0 * 22 * 256, 256, 22, 22};
    td.d[27] = {h2w, head_t + 1 * 22 * 256, 256, 22, 22};
    td.d[28] = {h3w, head_t + 2 * 22 * 256, 256, 22, 84};  // zero-pad global rows 66..127
    transpose_kernel<<<dim3(256, 29), 256, 0, stream>>>(td);
    cvt_kernel<<<VOCAB, 256, 0, stream>>>(letE, letEbf, VOCAB * 256);

    wide_gem_kernel<<<dim3(NTOK / 16), 256, 0, stream>>>(
        roots, letEbf, rpw_t, rpb, rlg, rlb, gem, catin);
    wide_pe_kernel<<<dim3(NTOK / 16), 256, 0, stream>>>(
        catin, ipw_t, ipb, ilg, ilb, ln1g, ln1b, x, nrm);

    for (int l = 0; l < NLAYER; ++l) {
        mm_kernel<64, 64, 6><<<dim3(12, 64), 256, 0, stream>>>(
            nrm, qkv_t + l * 196608, qb + l * 256, nullptr, qbuf, NTOK, 256, 768,
            kb + l * 256, vb + l * 256, kbuf, vtb);
        attn_mfma_kernel<<<dim3(16, 32), 256, 0, stream>>>(qbuf, kbuf, vtb, aob,
                                                           dsc + l * 8, dss + l * 8);
        mm_wide_ln_kernel<<<dim3(NTOK / 16), 256, 0, stream>>>(
            aob, ow_t + l * 65536, ob + l * 256, x, nrm,
            ln2g + l * 256, ln2b + l * 256, 256);
        mm_kernel<64, 64, 2><<<dim3(16, 64), 256, 0, stream>>>(
            nrm, ff1w_t + l * 262144, ff1b + l * 1024, nullptr, hbb, NTOK, 256, 1024,
            nullptr, nullptr, nullptr, nullptr);
        const float* ng = (l == 3) ? olng : ln1g + (l + 1) * 256;
        const float* nb = (l == 3) ? olnb : ln1b + (l + 1) * 256;
        mm_wide_ln_kernel<<<dim3(NTOK / 16), 256, 0, stream>>>(
            hbb, ff2w_t + l * 262144, ff2b + l * 256, x, nrm, ng, nb, 1024);
    }
    mm_kernel<32, 64, 5><<<dim3(2, 128), 256, 0, stream>>>(
        nrm, head_t, h1b, (float*)d_out, nullptr, NTOK, 256, 128,
        h2b, h3b, nullptr, nullptr);
}